// Round 2
// baseline (3266.931 us; speedup 1.0000x reference)
//
#include <hip/hip_runtime.h>

#define LOOKBACK 96
#define HID 128
#define HORIZON 24
#define NLAYERS 3

// ---------------------------------------------------------------------------
// utility kernels
// ---------------------------------------------------------------------------
__global__ void deg_init_k(float* __restrict__ deg, int n) {
    int i = blockIdx.x * blockDim.x + threadIdx.x;
    if (i < n) deg[i] = 1.0f;   // self-loop contributes 1 to degree
}

__global__ void deg_count_k(const int* __restrict__ dst, float* __restrict__ deg, int E) {
    int e = blockIdx.x * blockDim.x + threadIdx.x;
    if (e < E) unsafeAtomicAdd(&deg[dst[e]], 1.0f);
}

__global__ void dinv_k(float* __restrict__ deg, int n) {
    int i = blockIdx.x * blockDim.x + threadIdx.x;
    if (i < n) deg[i] = rsqrtf(deg[i]);   // deg>0 always (self-loops)
}

__global__ void norm_k(const int* __restrict__ src, const int* __restrict__ dst,
                       const float* __restrict__ dinv, float* __restrict__ norm, int E) {
    int e = blockIdx.x * blockDim.x + threadIdx.x;
    if (e < E) norm[e] = dinv[src[e]] * dinv[dst[e]];
}

// agg[i][:] = hw[i][:] * dinv[i]^2   (self-loop term; also initializes agg)
__global__ void selfinit_k(const float* __restrict__ hw, const float* __restrict__ dinv,
                           float* __restrict__ agg, int n) {
    int idx = blockIdx.x * blockDim.x + threadIdx.x;   // n*32 threads
    int i = idx >> 5;
    int c = (idx & 31) * 4;
    if (i >= n) return;
    float s = dinv[i]; s *= s;
    float4 v = *(const float4*)&hw[(size_t)i * HID + c];
    v.x *= s; v.y *= s; v.z *= s; v.w *= s;
    *(float4*)&agg[(size_t)i * HID + c] = v;
}

// agg[dst][:] += hw[src][:] * norm[e]
__global__ void edge_agg_k(const int* __restrict__ src, const int* __restrict__ dst,
                           const float* __restrict__ norm, const float* __restrict__ hw,
                           float* __restrict__ agg, int E) {
    int idx = blockIdx.x * blockDim.x + threadIdx.x;   // E*32 threads
    int e = idx >> 5;
    int c = (idx & 31) * 4;
    if (e >= E) return;
    int s = src[e];
    int d = dst[e];
    float nm = norm[e];
    float4 v = *(const float4*)&hw[(size_t)s * HID + c];
    float* o = &agg[(size_t)d * HID + c];
    unsafeAtomicAdd(o + 0, v.x * nm);
    unsafeAtomicAdd(o + 1, v.y * nm);
    unsafeAtomicAdd(o + 2, v.z * nm);
    unsafeAtomicAdd(o + 3, v.w * nm);
}

// h = relu(agg + b)  (in place)
__global__ void finalize_k(float* __restrict__ h, const float* __restrict__ bias, int n) {
    int idx = blockIdx.x * blockDim.x + threadIdx.x;   // n*32 threads
    int i = idx >> 5;
    int c = (idx & 31) * 4;
    if (i >= n) return;
    float4 v = *(float4*)&h[(size_t)i * HID + c];
    v.x = fmaxf(v.x + bias[c + 0], 0.0f);
    v.y = fmaxf(v.y + bias[c + 1], 0.0f);
    v.z = fmaxf(v.z + bias[c + 2], 0.0f);
    v.w = fmaxf(v.w + bias[c + 3], 0.0f);
    *(float4*)&h[(size_t)i * HID + c] = v;
}

__global__ void copy_k(const float* __restrict__ in, float* __restrict__ out, int n4) {
    int i = blockIdx.x * blockDim.x + threadIdx.x;
    if (i < n4) ((float4*)out)[i] = ((const float4*)in)[i];
}

// ---------------------------------------------------------------------------
// GEMM: C[n][128] = A[n][K] @ B[K][128] (+ bias)
// tile: 128 rows x 64 cols per 256-thread block; grid.x = ceil(n/128)*2
// B fully staged in LDS; A staged in transposed k-chunks of 32.
// Each thread computes 8 rows x 4 cols.
// ---------------------------------------------------------------------------
template <int K, bool BIAS>
__global__ __launch_bounds__(256) void gemm_k(
    const float* __restrict__ A, const float* __restrict__ B,
    const float* __restrict__ bias, float* __restrict__ C, int n)
{
    constexpr int KC = 32;
    __shared__ float Bs[K][64];
    __shared__ float As[KC][132];   // transposed chunk, padded stride

    const int tid = threadIdx.x;
    const int bcol = (blockIdx.x & 1) * 64;
    const int brow = (blockIdx.x >> 1) * 128;

    // stage B tile [K][64]
    #pragma unroll
    for (int i = 0; i < K / 16; ++i) {
        int flat = tid + i * 256;          // float4 index
        int k = flat >> 4;
        int c4 = (flat & 15) * 4;
        *(float4*)&Bs[k][c4] = *(const float4*)&B[(size_t)k * HID + bcol + c4];
    }

    const int rg = tid >> 4;   // 0..15 -> rows rg*8..+7
    const int cg = tid & 15;   // 0..15 -> cols cg*4..+3

    float acc[8][4];
    #pragma unroll
    for (int i = 0; i < 8; ++i)
        #pragma unroll
        for (int j = 0; j < 4; ++j) acc[i][j] = 0.0f;

    const int nchunk = K / KC;
    for (int kt = 0; kt < nchunk; ++kt) {
        __syncthreads();
        // stage A chunk transposed: rows brow..+127, k in [kt*32, kt*32+32)
        #pragma unroll
        for (int i = 0; i < 4; ++i) {
            int flat = tid + i * 256;
            int r = flat >> 3;
            int k4 = (flat & 7) * 4;
            int row = brow + r;
            float4 v = make_float4(0.f, 0.f, 0.f, 0.f);
            if (row < n) v = *(const float4*)&A[(size_t)row * K + kt * KC + k4];
            As[k4 + 0][r] = v.x;
            As[k4 + 1][r] = v.y;
            As[k4 + 2][r] = v.z;
            As[k4 + 3][r] = v.w;
        }
        __syncthreads();

        #pragma unroll
        for (int kk = 0; kk < KC; ++kk) {
            float4 a0 = *(const float4*)&As[kk][rg * 8];
            float4 a1 = *(const float4*)&As[kk][rg * 8 + 4];
            float4 b4 = *(const float4*)&Bs[kt * KC + kk][cg * 4];
            float av[8] = {a0.x, a0.y, a0.z, a0.w, a1.x, a1.y, a1.z, a1.w};
            float bv[4] = {b4.x, b4.y, b4.z, b4.w};
            #pragma unroll
            for (int i = 0; i < 8; ++i)
                #pragma unroll
                for (int j = 0; j < 4; ++j)
                    acc[i][j] = fmaf(av[i], bv[j], acc[i][j]);
        }
    }

    const int c0 = bcol + cg * 4;
    #pragma unroll
    for (int i = 0; i < 8; ++i) {
        int row = brow + rg * 8 + i;
        if (row < n) {
            float4 v;
            v.x = acc[i][0]; v.y = acc[i][1]; v.z = acc[i][2]; v.w = acc[i][3];
            if (BIAS) {
                v.x += bias[c0 + 0]; v.y += bias[c0 + 1];
                v.z += bias[c0 + 2]; v.w += bias[c0 + 3];
            }
            *(float4*)&C[(size_t)row * HID + c0] = v;
        }
    }
}

// ---------------------------------------------------------------------------
// output GEMM: C[n][24] = A[n][128] @ W[128][24] + b
// block: 256 threads -> 32 rows; thread: 1 row x 3 cols
// ---------------------------------------------------------------------------
__global__ __launch_bounds__(256) void gemm_out_k(
    const float* __restrict__ A, const float* __restrict__ W,
    const float* __restrict__ bias, float* __restrict__ C, int n)
{
    __shared__ float Wls[HID][HORIZON];
    __shared__ float As[32][132];

    const int tid = threadIdx.x;
    const int brow = blockIdx.x * 32;

    for (int i = tid; i < HID * HORIZON; i += 256)
        Wls[i / HORIZON][i % HORIZON] = W[i];

    #pragma unroll
    for (int i = 0; i < 4; ++i) {
        int flat = tid + i * 256;
        int r = flat >> 5;
        int k4 = (flat & 31) * 4;
        int row = brow + r;
        float4 v = make_float4(0.f, 0.f, 0.f, 0.f);
        if (row < n) v = *(const float4*)&A[(size_t)row * HID + k4];
        *(float4*)&As[r][k4] = v;
    }
    __syncthreads();

    const int rowi = tid >> 3;        // 0..31
    const int cg = tid & 7;           // cols cg*3..+2
    const int c0 = cg * 3;
    float a0 = bias[c0 + 0], a1 = bias[c0 + 1], a2 = bias[c0 + 2];
    #pragma unroll 8
    for (int k = 0; k < HID; ++k) {
        float a = As[rowi][k];
        a0 = fmaf(a, Wls[k][c0 + 0], a0);
        a1 = fmaf(a, Wls[k][c0 + 1], a1);
        a2 = fmaf(a, Wls[k][c0 + 2], a2);
    }
    int row = brow + rowi;
    if (row < n) {
        C[(size_t)row * HORIZON + c0 + 0] = a0;
        C[(size_t)row * HORIZON + c0 + 1] = a1;
        C[(size_t)row * HORIZON + c0 + 2] = a2;
    }
}

// ---------------------------------------------------------------------------
extern "C" void kernel_launch(void* const* d_in, const int* in_sizes, int n_in,
                              void* d_out, int out_size, void* d_ws, size_t ws_size,
                              hipStream_t stream) {
    const float* x     = (const float*)d_in[0];
    const float* y     = (const float*)d_in[1];
    const int*   ei    = (const int*)d_in[2];     // int64 in ref -> int32 on device
    const float* W_in  = (const float*)d_in[3];
    const float* b_in  = (const float*)d_in[4];
    const float* Ws    = (const float*)d_in[5];
    const float* bs    = (const float*)d_in[6];
    const float* W_out = (const float*)d_in[7];
    const float* b_out = (const float*)d_in[8];
    float* out = (float*)d_out;

    const int n = in_sizes[0] / LOOKBACK;
    const int E = in_sizes[2] / 2;
    const int* src = ei;
    const int* dst = ei + E;

    float* ws   = (float*)d_ws;
    float* deg  = ws;                       // n  (becomes dinv in place)
    float* norm = deg + n;                  // E
    float* bufA = norm + E;                 // n*128
    float* bufB = bufA + (size_t)n * HID;   // n*128

    const int B = 256;
    deg_init_k<<<(n + B - 1) / B, B, 0, stream>>>(deg, n);
    deg_count_k<<<(E + B - 1) / B, B, 0, stream>>>(dst, deg, E);
    dinv_k<<<(n + B - 1) / B, B, 0, stream>>>(deg, n);
    norm_k<<<(E + B - 1) / B, B, 0, stream>>>(src, dst, deg, norm, E);

    const int gemm_grid = ((n + 127) / 128) * 2;
    gemm_k<LOOKBACK, true><<<gemm_grid, 256, 0, stream>>>(x, W_in, b_in, bufA, n);

    const int nv = n * 32;    // n*128/4 work items
    const int ev = E * 32;
    for (int l = 0; l < NLAYERS; ++l) {
        gemm_k<HID, false><<<gemm_grid, 256, 0, stream>>>(bufA, Ws + (size_t)l * HID * HID, nullptr, bufB, n);
        selfinit_k<<<(nv + B - 1) / B, B, 0, stream>>>(bufB, deg, bufA, n);
        edge_agg_k<<<(ev + B - 1) / B, B, 0, stream>>>(src, dst, norm, bufB, bufA, E);
        finalize_k<<<(nv + B - 1) / B, B, 0, stream>>>(bufA, bs + (size_t)l * HID, n);
    }

    gemm_out_k<<<(n + 31) / 32, 256, 0, stream>>>(bufA, W_out, b_out, out, n);

    const int y4 = n * HORIZON / 4;
    copy_k<<<(y4 + B - 1) / B, B, 0, stream>>>(y, out + (size_t)n * HORIZON, y4);
}

// Round 3
// 463.821 us; speedup vs baseline: 7.0435x; 7.0435x over previous
//
#include <hip/hip_runtime.h>

#define LOOKBACK 96
#define HID 128
#define HORIZON 24
#define NLAYERS 3

// ---------------------------------------------------------------------------
// CSR build
// ---------------------------------------------------------------------------
__global__ void zero_counts_k(int* __restrict__ counts, int n) {
    int i = blockIdx.x * blockDim.x + threadIdx.x;
    if (i < n) counts[i] = 0;
}

__global__ void hist_k(const int* __restrict__ dst, int* __restrict__ counts, int E) {
    int e = blockIdx.x * blockDim.x + threadIdx.x;
    if (e < E) atomicAdd(&counts[dst[e]], 1);
}

__global__ void dinv_k(const int* __restrict__ counts, float* __restrict__ dinv, int n) {
    int i = blockIdx.x * blockDim.x + threadIdx.x;
    if (i < n) dinv[i] = rsqrtf((float)counts[i] + 1.0f);   // +1 self loop
}

// per-block (1024 nodes) sum of counts
__global__ __launch_bounds__(1024) void bsum_k(const int* __restrict__ counts,
                                               int* __restrict__ bsum, int n) {
    __shared__ int s[1024];
    int t = threadIdx.x;
    int i = blockIdx.x * 1024 + t;
    s[t] = (i < n) ? counts[i] : 0;
    __syncthreads();
    for (int off = 512; off > 0; off >>= 1) {
        if (t < off) s[t] += s[t + off];
        __syncthreads();
    }
    if (t == 0) bsum[blockIdx.x] = s[0];
}

// exclusive scan of block sums (single block, nb <= 1024)
__global__ __launch_bounds__(1024) void scan_bsum_k(int* __restrict__ bsum, int nb) {
    __shared__ int s[1024];
    int t = threadIdx.x;
    int orig = (t < nb) ? bsum[t] : 0;
    s[t] = orig;
    __syncthreads();
    for (int off = 1; off < 1024; off <<= 1) {
        int x = s[t];
        int y = (t >= off) ? s[t - off] : 0;
        __syncthreads();
        s[t] = x + y;
        __syncthreads();
    }
    if (t < nb) bsum[t] = s[t] - orig;   // exclusive
}

// local scan + add block offset -> offsets, cursor
__global__ __launch_bounds__(1024) void scan_local_k(const int* __restrict__ counts,
                                                     const int* __restrict__ bsum,
                                                     int* __restrict__ offsets,
                                                     int* __restrict__ cursor, int n) {
    __shared__ int s[1024];
    int t = threadIdx.x;
    int i = blockIdx.x * 1024 + t;
    int c = (i < n) ? counts[i] : 0;
    s[t] = c;
    __syncthreads();
    for (int off = 1; off < 1024; off <<= 1) {
        int x = s[t];
        int y = (t >= off) ? s[t - off] : 0;
        __syncthreads();
        s[t] = x + y;
        __syncthreads();
    }
    if (i < n) {
        int o = bsum[blockIdx.x] + s[t] - c;   // exclusive
        offsets[i] = o;
        cursor[i] = o;
    }
}

// scatter edges into CSR buckets; store src index and dinv[src]
__global__ void scatter_k(const int* __restrict__ src, const int* __restrict__ dst,
                          const float* __restrict__ dinv,
                          int* __restrict__ cursor,
                          int* __restrict__ src_sorted, float* __restrict__ w_sorted, int E) {
    int e = blockIdx.x * blockDim.x + threadIdx.x;
    if (e >= E) return;
    int d = dst[e];
    int s = src[e];
    int pos = atomicAdd(&cursor[d], 1);
    src_sorted[pos] = s;
    w_sorted[pos] = dinv[s];
}

// ---------------------------------------------------------------------------
// fused aggregation: one wave per node, 2 features per lane
// out[i] = relu( dinv[i]*Sum_e dinv[src]*hw[src] + dinv[i]^2*hw[i] + bias )
// ---------------------------------------------------------------------------
__global__ __launch_bounds__(256) void agg_k(
    const float* __restrict__ hw, float* __restrict__ out,
    const float* __restrict__ dinv,
    const int* __restrict__ offsets, const int* __restrict__ counts,
    const int* __restrict__ src_sorted, const float* __restrict__ w_sorted,
    const float* __restrict__ bias, int n)
{
    int node = (blockIdx.x * 256 + threadIdx.x) >> 6;
    if (node >= n) return;
    int lane = threadIdx.x & 63;
    int c = lane * 2;

    float di = dinv[node];
    float2 self = *(const float2*)&hw[(size_t)node * HID + c];
    float s0 = 0.0f, s1 = 0.0f;

    int off = offsets[node];
    int end = off + counts[node];
    for (int e = off; e < end; ++e) {
        int s = src_sorted[e];
        float w = w_sorted[e];
        float2 u = *(const float2*)&hw[(size_t)s * HID + c];
        s0 = fmaf(w, u.x, s0);
        s1 = fmaf(w, u.y, s1);
    }

    float r0 = fmaf(di, s0, di * di * self.x) + bias[c + 0];
    float r1 = fmaf(di, s1, di * di * self.y) + bias[c + 1];
    float2 res;
    res.x = fmaxf(r0, 0.0f);
    res.y = fmaxf(r1, 0.0f);
    *(float2*)&out[(size_t)node * HID + c] = res;
}

__global__ void copy_k(const float* __restrict__ in, float* __restrict__ out, int n4) {
    int i = blockIdx.x * blockDim.x + threadIdx.x;
    if (i < n4) ((float4*)out)[i] = ((const float4*)in)[i];
}

// ---------------------------------------------------------------------------
// GEMM: C[n][128] = A[n][K] @ B[K][128] (+ bias)
// ---------------------------------------------------------------------------
template <int K, bool BIAS>
__global__ __launch_bounds__(256) void gemm_k(
    const float* __restrict__ A, const float* __restrict__ B,
    const float* __restrict__ bias, float* __restrict__ C, int n)
{
    constexpr int KC = 32;
    __shared__ float Bs[K][64];
    __shared__ float As[KC][132];

    const int tid = threadIdx.x;
    const int bcol = (blockIdx.x & 1) * 64;
    const int brow = (blockIdx.x >> 1) * 128;

    #pragma unroll
    for (int i = 0; i < K / 16; ++i) {
        int flat = tid + i * 256;
        int k = flat >> 4;
        int c4 = (flat & 15) * 4;
        *(float4*)&Bs[k][c4] = *(const float4*)&B[(size_t)k * HID + bcol + c4];
    }

    const int rg = tid >> 4;
    const int cg = tid & 15;

    float acc[8][4];
    #pragma unroll
    for (int i = 0; i < 8; ++i)
        #pragma unroll
        for (int j = 0; j < 4; ++j) acc[i][j] = 0.0f;

    const int nchunk = K / KC;
    for (int kt = 0; kt < nchunk; ++kt) {
        __syncthreads();
        #pragma unroll
        for (int i = 0; i < 4; ++i) {
            int flat = tid + i * 256;
            int r = flat >> 3;
            int k4 = (flat & 7) * 4;
            int row = brow + r;
            float4 v = make_float4(0.f, 0.f, 0.f, 0.f);
            if (row < n) v = *(const float4*)&A[(size_t)row * K + kt * KC + k4];
            As[k4 + 0][r] = v.x;
            As[k4 + 1][r] = v.y;
            As[k4 + 2][r] = v.z;
            As[k4 + 3][r] = v.w;
        }
        __syncthreads();

        #pragma unroll
        for (int kk = 0; kk < KC; ++kk) {
            float4 a0 = *(const float4*)&As[kk][rg * 8];
            float4 a1 = *(const float4*)&As[kk][rg * 8 + 4];
            float4 b4 = *(const float4*)&Bs[kt * KC + kk][cg * 4];
            float av[8] = {a0.x, a0.y, a0.z, a0.w, a1.x, a1.y, a1.z, a1.w};
            float bv[4] = {b4.x, b4.y, b4.z, b4.w};
            #pragma unroll
            for (int i = 0; i < 8; ++i)
                #pragma unroll
                for (int j = 0; j < 4; ++j)
                    acc[i][j] = fmaf(av[i], bv[j], acc[i][j]);
        }
    }

    const int c0 = bcol + cg * 4;
    #pragma unroll
    for (int i = 0; i < 8; ++i) {
        int row = brow + rg * 8 + i;
        if (row < n) {
            float4 v;
            v.x = acc[i][0]; v.y = acc[i][1]; v.z = acc[i][2]; v.w = acc[i][3];
            if (BIAS) {
                v.x += bias[c0 + 0]; v.y += bias[c0 + 1];
                v.z += bias[c0 + 2]; v.w += bias[c0 + 3];
            }
            *(float4*)&C[(size_t)row * HID + c0] = v;
        }
    }
}

// ---------------------------------------------------------------------------
// output GEMM: C[n][24] = A[n][128] @ W[128][24] + b
// ---------------------------------------------------------------------------
__global__ __launch_bounds__(256) void gemm_out_k(
    const float* __restrict__ A, const float* __restrict__ W,
    const float* __restrict__ bias, float* __restrict__ C, int n)
{
    __shared__ float Wls[HID][HORIZON];
    __shared__ float As[32][132];

    const int tid = threadIdx.x;
    const int brow = blockIdx.x * 32;

    for (int i = tid; i < HID * HORIZON; i += 256)
        Wls[i / HORIZON][i % HORIZON] = W[i];

    #pragma unroll
    for (int i = 0; i < 4; ++i) {
        int flat = tid + i * 256;
        int r = flat >> 5;
        int k4 = (flat & 31) * 4;
        int row = brow + r;
        float4 v = make_float4(0.f, 0.f, 0.f, 0.f);
        if (row < n) v = *(const float4*)&A[(size_t)row * HID + k4];
        *(float4*)&As[r][k4] = v;
    }
    __syncthreads();

    const int rowi = tid >> 3;
    const int cg = tid & 7;
    const int c0 = cg * 3;
    float a0 = bias[c0 + 0], a1 = bias[c0 + 1], a2 = bias[c0 + 2];
    #pragma unroll 8
    for (int k = 0; k < HID; ++k) {
        float a = As[rowi][k];
        a0 = fmaf(a, Wls[k][c0 + 0], a0);
        a1 = fmaf(a, Wls[k][c0 + 1], a1);
        a2 = fmaf(a, Wls[k][c0 + 2], a2);
    }
    int row = brow + rowi;
    if (row < n) {
        C[(size_t)row * HORIZON + c0 + 0] = a0;
        C[(size_t)row * HORIZON + c0 + 1] = a1;
        C[(size_t)row * HORIZON + c0 + 2] = a2;
    }
}

// ---------------------------------------------------------------------------
extern "C" void kernel_launch(void* const* d_in, const int* in_sizes, int n_in,
                              void* d_out, int out_size, void* d_ws, size_t ws_size,
                              hipStream_t stream) {
    const float* x     = (const float*)d_in[0];
    const float* y     = (const float*)d_in[1];
    const int*   ei    = (const int*)d_in[2];     // int64 in ref -> int32 on device
    const float* W_in  = (const float*)d_in[3];
    const float* b_in  = (const float*)d_in[4];
    const float* Ws    = (const float*)d_in[5];
    const float* bs    = (const float*)d_in[6];
    const float* W_out = (const float*)d_in[7];
    const float* b_out = (const float*)d_in[8];
    float* out = (float*)d_out;

    const int n = in_sizes[0] / LOOKBACK;
    const int E = in_sizes[2] / 2;
    const int* src = ei;
    const int* dst = ei + E;
    const int nb = (n + 1023) / 1024;

    // workspace layout
    char* p = (char*)d_ws;
    float* dinv       = (float*)p;            p += (size_t)n * 4;
    int*   counts     = (int*)p;              p += (size_t)n * 4;
    int*   offsets    = (int*)p;              p += (size_t)n * 4;
    int*   cursor     = (int*)p;              p += (size_t)n * 4;
    int*   bsum       = (int*)p;              p += (size_t)1024 * 4;
    int*   src_sorted = (int*)p;              p += (size_t)E * 4;
    float* w_sorted   = (float*)p;            p += (size_t)E * 4;
    float* bufA       = (float*)p;            p += (size_t)n * HID * 4;
    float* bufB       = (float*)p;

    const int B = 256;
    // ---- CSR build ----
    zero_counts_k<<<(n + B - 1) / B, B, 0, stream>>>(counts, n);
    hist_k<<<(E + B - 1) / B, B, 0, stream>>>(dst, counts, E);
    dinv_k<<<(n + B - 1) / B, B, 0, stream>>>(counts, dinv, n);
    bsum_k<<<nb, 1024, 0, stream>>>(counts, bsum, n);
    scan_bsum_k<<<1, 1024, 0, stream>>>(bsum, nb);
    scan_local_k<<<nb, 1024, 0, stream>>>(counts, bsum, offsets, cursor, n);
    scatter_k<<<(E + B - 1) / B, B, 0, stream>>>(src, dst, dinv, cursor, src_sorted, w_sorted, E);

    // ---- network ----
    const int gemm_grid = ((n + 127) / 128) * 2;
    gemm_k<LOOKBACK, true><<<gemm_grid, 256, 0, stream>>>(x, W_in, b_in, bufA, n);

    const int agg_grid = (n * 64 + 255) / 256;   // one wave per node
    for (int l = 0; l < NLAYERS; ++l) {
        gemm_k<HID, false><<<gemm_grid, 256, 0, stream>>>(bufA, Ws + (size_t)l * HID * HID, nullptr, bufB, n);
        agg_k<<<agg_grid, 256, 0, stream>>>(bufB, bufA, dinv, offsets, counts,
                                            src_sorted, w_sorted, bs + (size_t)l * HID, n);
    }

    gemm_out_k<<<(n + 31) / 32, 256, 0, stream>>>(bufA, W_out, b_out, out, n);

    const int y4 = n * HORIZON / 4;
    copy_k<<<(y4 + B - 1) / B, B, 0, stream>>>(y, out + (size_t)n * HORIZON, y4);
}

// Round 4
// 272.247 us; speedup vs baseline: 11.9999x; 1.7037x over previous
//
#include <hip/hip_runtime.h>
#include <hip/hip_bf16.h>

#define LOOKBACK 96
#define HID 128
#define HORIZON 24
#define NLAYERS 3

typedef __attribute__((ext_vector_type(8))) short short8v;
typedef __attribute__((ext_vector_type(4))) float f32x4;

__device__ __forceinline__ float bf_lo(uint u) { return __uint_as_float(u << 16); }
__device__ __forceinline__ float bf_hi(uint u) { return __uint_as_float(u & 0xffff0000u); }
__device__ __forceinline__ ushort f2bf(float f) {
    __hip_bfloat16 h = __float2bfloat16(f);
    return *(ushort*)&h;
}

// ---------------------------------------------------------------------------
// casts
// ---------------------------------------------------------------------------
__global__ void cast_k(const float* __restrict__ in, ushort* __restrict__ out, int nelem) {
    int i = blockIdx.x * blockDim.x + threadIdx.x;
    int idx = i * 2;
    if (idx + 1 < nelem) {
        float2 v = *(const float2*)&in[idx];
        uint p = (uint)f2bf(v.x) | ((uint)f2bf(v.y) << 16);
        *(uint*)&out[idx] = p;
    } else if (idx < nelem) {
        out[idx] = f2bf(in[idx]);
    }
}

// ---------------------------------------------------------------------------
// CSR build
// ---------------------------------------------------------------------------
__global__ void zero_counts_k(int* __restrict__ counts, int n) {
    int i = blockIdx.x * blockDim.x + threadIdx.x;
    if (i < n) counts[i] = 0;
}

__global__ void hist_k(const int* __restrict__ dst, int* __restrict__ counts, int E) {
    int e = blockIdx.x * blockDim.x + threadIdx.x;
    if (e < E) atomicAdd(&counts[dst[e]], 1);
}

__global__ void dinv_k(const int* __restrict__ counts, float* __restrict__ dinv, int n) {
    int i = blockIdx.x * blockDim.x + threadIdx.x;
    if (i < n) dinv[i] = rsqrtf((float)counts[i] + 1.0f);   // +1 self loop
}

__global__ __launch_bounds__(1024) void bsum_k(const int* __restrict__ counts,
                                               int* __restrict__ bsum, int n) {
    __shared__ int s[1024];
    int t = threadIdx.x;
    int i = blockIdx.x * 1024 + t;
    s[t] = (i < n) ? counts[i] : 0;
    __syncthreads();
    for (int off = 512; off > 0; off >>= 1) {
        if (t < off) s[t] += s[t + off];
        __syncthreads();
    }
    if (t == 0) bsum[blockIdx.x] = s[0];
}

__global__ __launch_bounds__(1024) void scan_bsum_k(int* __restrict__ bsum, int nb) {
    __shared__ int s[1024];
    int t = threadIdx.x;
    int orig = (t < nb) ? bsum[t] : 0;
    s[t] = orig;
    __syncthreads();
    for (int off = 1; off < 1024; off <<= 1) {
        int x = s[t];
        int y = (t >= off) ? s[t - off] : 0;
        __syncthreads();
        s[t] = x + y;
        __syncthreads();
    }
    if (t < nb) bsum[t] = s[t] - orig;   // exclusive
}

__global__ __launch_bounds__(1024) void scan_local_k(const int* __restrict__ counts,
                                                     const int* __restrict__ bsum,
                                                     int* __restrict__ offsets,
                                                     int* __restrict__ cursor, int n) {
    __shared__ int s[1024];
    int t = threadIdx.x;
    int i = blockIdx.x * 1024 + t;
    int c = (i < n) ? counts[i] : 0;
    s[t] = c;
    __syncthreads();
    for (int off = 1; off < 1024; off <<= 1) {
        int x = s[t];
        int y = (t >= off) ? s[t - off] : 0;
        __syncthreads();
        s[t] = x + y;
        __syncthreads();
    }
    if (i < n) {
        int o = bsum[blockIdx.x] + s[t] - c;
        offsets[i] = o;
        cursor[i] = o;
    }
}

// scatter edges into CSR buckets: (src, bits(dinv[src]))
__global__ void scatter_k(const int* __restrict__ src, const int* __restrict__ dst,
                          const float* __restrict__ dinv,
                          int* __restrict__ cursor, int2* __restrict__ edges, int E) {
    int e = blockIdx.x * blockDim.x + threadIdx.x;
    if (e >= E) return;
    int d = dst[e];
    int s = src[e];
    int pos = atomicAdd(&cursor[d], 1);
    int2 v;
    v.x = s;
    v.y = __float_as_int(dinv[s]);
    edges[pos] = v;
}

// ---------------------------------------------------------------------------
// fused aggregation (bf16 in/out, fp32 accumulate)
// out[i] = relu( dinv[i]*Sum dinv[src]*hw[src] + dinv[i]^2*hw[i] + bias )
// one wave per node, 2 features per lane
// ---------------------------------------------------------------------------
__global__ __launch_bounds__(256) void agg_k(
    const ushort* __restrict__ hw, ushort* __restrict__ out,
    const float* __restrict__ dinv,
    const int* __restrict__ offsets, const int* __restrict__ counts,
    const int2* __restrict__ edges,
    const float* __restrict__ bias, int n)
{
    int node = (blockIdx.x * 256 + threadIdx.x) >> 6;
    if (node >= n) return;
    int lane = threadIdx.x & 63;
    int c = lane * 2;

    float di = dinv[node];
    uint sv = *(const uint*)&hw[(size_t)node * HID + c];
    float s0 = 0.0f, s1 = 0.0f;

    int cnt = counts[node];
    const int2* ep = edges + offsets[node];
    int i = 0;
    for (; i + 4 <= cnt; i += 4) {
        int2 e0 = ep[i], e1 = ep[i + 1], e2 = ep[i + 2], e3 = ep[i + 3];
        uint u0 = *(const uint*)&hw[(size_t)e0.x * HID + c];
        uint u1 = *(const uint*)&hw[(size_t)e1.x * HID + c];
        uint u2 = *(const uint*)&hw[(size_t)e2.x * HID + c];
        uint u3 = *(const uint*)&hw[(size_t)e3.x * HID + c];
        float w0 = __int_as_float(e0.y), w1 = __int_as_float(e1.y);
        float w2 = __int_as_float(e2.y), w3 = __int_as_float(e3.y);
        s0 = fmaf(w0, bf_lo(u0), s0); s1 = fmaf(w0, bf_hi(u0), s1);
        s0 = fmaf(w1, bf_lo(u1), s0); s1 = fmaf(w1, bf_hi(u1), s1);
        s0 = fmaf(w2, bf_lo(u2), s0); s1 = fmaf(w2, bf_hi(u2), s1);
        s0 = fmaf(w3, bf_lo(u3), s0); s1 = fmaf(w3, bf_hi(u3), s1);
    }
    for (; i < cnt; ++i) {
        int2 e0 = ep[i];
        uint u0 = *(const uint*)&hw[(size_t)e0.x * HID + c];
        float w0 = __int_as_float(e0.y);
        s0 = fmaf(w0, bf_lo(u0), s0);
        s1 = fmaf(w0, bf_hi(u0), s1);
    }

    float dd = di * di;
    float r0 = fmaf(di, s0, dd * bf_lo(sv)) + bias[c + 0];
    float r1 = fmaf(di, s1, dd * bf_hi(sv)) + bias[c + 1];
    r0 = fmaxf(r0, 0.0f);
    r1 = fmaxf(r1, 0.0f);
    uint p = (uint)f2bf(r0) | ((uint)f2bf(r1) << 16);
    *(uint*)&out[(size_t)node * HID + c] = p;
}

__global__ void copy_k(const float* __restrict__ in, float* __restrict__ out, int n4) {
    int i = blockIdx.x * blockDim.x + threadIdx.x;
    if (i < n4) ((float4*)out)[i] = ((const float4*)in)[i];
}

// ---------------------------------------------------------------------------
// MFMA GEMM: C_bf16[n][128] = A_bf16[n][K] @ B_bf16[K][128] (+ bias)
// block: 256 threads = 4 waves; tile 64 rows x 128 cols (16 rows/wave)
// B staged transposed in LDS (stride 136: conflict-free ds_read_b128)
// ---------------------------------------------------------------------------
template <int K, bool BIAS>
__global__ __launch_bounds__(256) void mfma_gemm_k(
    const ushort* __restrict__ A, const ushort* __restrict__ B,
    const float* __restrict__ bias, ushort* __restrict__ C, int n)
{
    constexpr int KSTEPS = K / 32;
    __shared__ ushort Bt[128][136];

    const int tid = threadIdx.x;
    const int wid = tid >> 6;
    const int lane = tid & 63;
    const int brow = blockIdx.x * 64;

    // stage B transposed: Bt[col][k] = B[k][col]
    for (int i = tid; i < K * 64; i += 256) {
        uint v = ((const uint*)B)[i];
        int idx = 2 * i;
        int k = idx >> 7;
        int cc = idx & 127;
        Bt[cc][k] = (ushort)(v & 0xffffu);
        Bt[cc + 1][k] = (ushort)(v >> 16);
    }
    __syncthreads();

    // A fragment base: row = l&15 (+wave offset), k-chunk = (l>>4)*8
    const int arow = brow + wid * 16 + (lane & 15);
    const int rowc = (arow < n) ? arow : (n - 1);
    const ushort* aptr = &A[(size_t)rowc * K + (lane >> 4) * 8];

    f32x4 acc[8];
    #pragma unroll
    for (int j = 0; j < 8; ++j) acc[j] = (f32x4){0.f, 0.f, 0.f, 0.f};

    #pragma unroll
    for (int kt = 0; kt < KSTEPS; ++kt) {
        short8v a = *(const short8v*)(aptr + kt * 32);
        #pragma unroll
        for (int j = 0; j < 8; ++j) {
            short8v b = *(const short8v*)&Bt[j * 16 + (lane & 15)][kt * 32 + (lane >> 4) * 8];
            acc[j] = __builtin_amdgcn_mfma_f32_16x16x32_bf16(a, b, acc[j], 0, 0, 0);
        }
    }

    // epilogue: C/D layout col = lane&15, row = (lane>>4)*4 + reg
    const int r0 = brow + wid * 16 + (lane >> 4) * 4;
    const int cl = lane & 15;
    #pragma unroll
    for (int j = 0; j < 8; ++j) {
        int col = j * 16 + cl;
        float bv = BIAS ? bias[col] : 0.0f;
        #pragma unroll
        for (int r = 0; r < 4; ++r) {
            int row = r0 + r;
            if (row < n) {
                C[(size_t)row * HID + col] = f2bf(acc[j][r] + bv);
            }
        }
    }
}

// ---------------------------------------------------------------------------
// output GEMM: C_f32[n][24] = A_bf16[n][128] @ W_f32[128][24] + b
// ---------------------------------------------------------------------------
__global__ __launch_bounds__(256) void gemm_out_k(
    const ushort* __restrict__ A, const float* __restrict__ W,
    const float* __restrict__ bias, float* __restrict__ C, int n)
{
    __shared__ float Wls[HID][HORIZON];
    __shared__ float As[32][132];

    const int tid = threadIdx.x;
    const int brow = blockIdx.x * 32;

    for (int i = tid; i < HID * HORIZON; i += 256)
        Wls[i / HORIZON][i % HORIZON] = W[i];

    for (int i = tid; i < 32 * 64; i += 256) {     // uints: 32 rows * 128 cols / 2
        int idx = 2 * i;
        int r = idx >> 7;
        int cc = idx & 127;
        int row = brow + r;
        uint v = 0;
        if (row < n) v = *(const uint*)&A[(size_t)row * HID + cc];
        As[r][cc] = bf_lo(v);
        As[r][cc + 1] = bf_hi(v);
    }
    __syncthreads();

    const int rowi = tid >> 3;
    const int cg = tid & 7;
    const int c0 = cg * 3;
    float a0 = bias[c0 + 0], a1 = bias[c0 + 1], a2 = bias[c0 + 2];
    #pragma unroll 8
    for (int k = 0; k < HID; ++k) {
        float a = As[rowi][k];
        a0 = fmaf(a, Wls[k][c0 + 0], a0);
        a1 = fmaf(a, Wls[k][c0 + 1], a1);
        a2 = fmaf(a, Wls[k][c0 + 2], a2);
    }
    int row = brow + rowi;
    if (row < n) {
        C[(size_t)row * HORIZON + c0 + 0] = a0;
        C[(size_t)row * HORIZON + c0 + 1] = a1;
        C[(size_t)row * HORIZON + c0 + 2] = a2;
    }
}

// ---------------------------------------------------------------------------
extern "C" void kernel_launch(void* const* d_in, const int* in_sizes, int n_in,
                              void* d_out, int out_size, void* d_ws, size_t ws_size,
                              hipStream_t stream) {
    const float* x     = (const float*)d_in[0];
    const float* y     = (const float*)d_in[1];
    const int*   ei    = (const int*)d_in[2];     // int64 in ref -> int32 on device
    const float* W_in  = (const float*)d_in[3];
    const float* b_in  = (const float*)d_in[4];
    const float* Ws    = (const float*)d_in[5];
    const float* bs    = (const float*)d_in[6];
    const float* W_out = (const float*)d_in[7];
    const float* b_out = (const float*)d_in[8];
    float* out = (float*)d_out;

    const int n = in_sizes[0] / LOOKBACK;
    const int E = in_sizes[2] / 2;
    const int* src = ei;
    const int* dst = ei + E;
    const int nb = (n + 1023) / 1024;

    // workspace layout (all chunks 16B-aligned for n,E used here)
    char* p = (char*)d_ws;
    float*  dinv    = (float*)p;   p += (size_t)n * 4;
    int*    counts  = (int*)p;     p += (size_t)n * 4;
    int*    offsets = (int*)p;     p += (size_t)n * 4;
    int*    cursor  = (int*)p;     p += (size_t)n * 4;
    int*    bsum    = (int*)p;     p += (size_t)1024 * 4;
    int2*   edges   = (int2*)p;    p += (size_t)E * 8;
    ushort* x_b     = (ushort*)p;  p += (size_t)n * LOOKBACK * 2;
    ushort* Win_b   = (ushort*)p;  p += (size_t)LOOKBACK * HID * 2;
    ushort* Ws_b    = (ushort*)p;  p += (size_t)NLAYERS * HID * HID * 2;
    ushort* bufA    = (ushort*)p;  p += (size_t)n * HID * 2;
    ushort* bufB    = (ushort*)p;

    const int B = 256;
    // ---- casts ----
    const int nx = n * LOOKBACK;
    cast_k<<<(nx / 2 + B - 1) / B, B, 0, stream>>>(x, x_b, nx);
    cast_k<<<(LOOKBACK * HID / 2 + B - 1) / B, B, 0, stream>>>(W_in, Win_b, LOOKBACK * HID);
    cast_k<<<(NLAYERS * HID * HID / 2 + B - 1) / B, B, 0, stream>>>(Ws, Ws_b, NLAYERS * HID * HID);

    // ---- CSR build ----
    zero_counts_k<<<(n + B - 1) / B, B, 0, stream>>>(counts, n);
    hist_k<<<(E + B - 1) / B, B, 0, stream>>>(dst, counts, E);
    dinv_k<<<(n + B - 1) / B, B, 0, stream>>>(counts, dinv, n);
    bsum_k<<<nb, 1024, 0, stream>>>(counts, bsum, n);
    scan_bsum_k<<<1, 1024, 0, stream>>>(bsum, nb);
    scan_local_k<<<nb, 1024, 0, stream>>>(counts, bsum, offsets, cursor, n);
    scatter_k<<<(E + B - 1) / B, B, 0, stream>>>(src, dst, dinv, cursor, edges, E);

    // ---- network ----
    const int gemm_grid = (n + 63) / 64;
    mfma_gemm_k<LOOKBACK, true><<<gemm_grid, 256, 0, stream>>>(x_b, Win_b, b_in, bufA, n);

    const int agg_grid = (n * 64 + 255) / 256;
    for (int l = 0; l < NLAYERS; ++l) {
        mfma_gemm_k<HID, false><<<gemm_grid, 256, 0, stream>>>(
            bufA, Ws_b + (size_t)l * HID * HID, nullptr, bufB, n);
        agg_k<<<agg_grid, 256, 0, stream>>>(bufB, bufA, dinv, offsets, counts,
                                            edges, bs + (size_t)l * HID, n);
    }

    gemm_out_k<<<(n + 31) / 32, 256, 0, stream>>>(bufA, W_out, b_out, out, n);

    const int y4 = n * HORIZON / 4;
    copy_k<<<(y4 + B - 1) / B, B, 0, stream>>>(y, out + (size_t)n * HORIZON, y4);
}

// Round 5
// 262.664 us; speedup vs baseline: 12.4377x; 1.0365x over previous
//
#include <hip/hip_runtime.h>
#include <hip/hip_bf16.h>

#define LOOKBACK 96
#define HID 128
#define HORIZON 24
#define NLAYERS 3

typedef __attribute__((ext_vector_type(8))) short short8v;
typedef __attribute__((ext_vector_type(4))) float f32x4;

__device__ __forceinline__ float bf_lo(uint u) { return __uint_as_float(u << 16); }
__device__ __forceinline__ float bf_hi(uint u) { return __uint_as_float(u & 0xffff0000u); }
__device__ __forceinline__ ushort f2bf(float f) {
    __hip_bfloat16 h = __float2bfloat16(f);
    return *(ushort*)&h;
}

// ---------------------------------------------------------------------------
// CSR build
// ---------------------------------------------------------------------------
__global__ void zero_counts_k(int* __restrict__ counts, int n) {
    int i = blockIdx.x * blockDim.x + threadIdx.x;
    if (i < n) counts[i] = 0;
}

__global__ void hist_k(const int* __restrict__ dst, int* __restrict__ counts, int E) {
    int e = blockIdx.x * blockDim.x + threadIdx.x;
    if (e < E) atomicAdd(&counts[dst[e]], 1);
}

__global__ void dinv_k(const int* __restrict__ counts, float* __restrict__ dinv, int n) {
    int i = blockIdx.x * blockDim.x + threadIdx.x;
    if (i < n) dinv[i] = rsqrtf((float)counts[i] + 1.0f);   // +1 self loop
}

__global__ __launch_bounds__(1024) void bsum_k(const int* __restrict__ counts,
                                               int* __restrict__ bsum, int n) {
    __shared__ int s[1024];
    int t = threadIdx.x;
    int i = blockIdx.x * 1024 + t;
    s[t] = (i < n) ? counts[i] : 0;
    __syncthreads();
    for (int off = 512; off > 0; off >>= 1) {
        if (t < off) s[t] += s[t + off];
        __syncthreads();
    }
    if (t == 0) bsum[blockIdx.x] = s[0];
}

__global__ __launch_bounds__(1024) void scan_bsum_k(int* __restrict__ bsum, int nb) {
    __shared__ int s[1024];
    int t = threadIdx.x;
    int orig = (t < nb) ? bsum[t] : 0;
    s[t] = orig;
    __syncthreads();
    for (int off = 1; off < 1024; off <<= 1) {
        int x = s[t];
        int y = (t >= off) ? s[t - off] : 0;
        __syncthreads();
        s[t] = x + y;
        __syncthreads();
    }
    if (t < nb) bsum[t] = s[t] - orig;   // exclusive
}

__global__ __launch_bounds__(1024) void scan_local_k(const int* __restrict__ counts,
                                                     const int* __restrict__ bsum,
                                                     int* __restrict__ offsets,
                                                     int* __restrict__ cursor, int n) {
    __shared__ int s[1024];
    int t = threadIdx.x;
    int i = blockIdx.x * 1024 + t;
    int c = (i < n) ? counts[i] : 0;
    s[t] = c;
    __syncthreads();
    for (int off = 1; off < 1024; off <<= 1) {
        int x = s[t];
        int y = (t >= off) ? s[t - off] : 0;
        __syncthreads();
        s[t] = x + y;
        __syncthreads();
    }
    if (i < n) {
        int o = bsum[blockIdx.x] + s[t] - c;
        offsets[i] = o;
        cursor[i] = o;
    }
}

// scatter edges into CSR buckets: src index only
__global__ void scatter_k(const int* __restrict__ src, const int* __restrict__ dst,
                          int* __restrict__ cursor, int* __restrict__ srcs, int E) {
    int e = blockIdx.x * blockDim.x + threadIdx.x;
    if (e >= E) return;
    int d = dst[e];
    int pos = atomicAdd(&cursor[d], 1);
    srcs[pos] = src[e];
}

// ---------------------------------------------------------------------------
// fused aggregation (bf16 in/out, fp32 accumulate), hw is pre-scaled by dinv:
// out[i] = relu( dinv[i]*( zh[i] + Sum_e zh[src] ) + bias )
// one wave per node, 2 features per lane
// ---------------------------------------------------------------------------
__global__ __launch_bounds__(256) void agg_k(
    const ushort* __restrict__ zh, ushort* __restrict__ out,
    const float* __restrict__ dinv,
    const int* __restrict__ offsets, const int* __restrict__ counts,
    const int* __restrict__ srcs,
    const float* __restrict__ bias, int n)
{
    int node = (blockIdx.x * 256 + threadIdx.x) >> 6;
    if (node >= n) return;
    node = __builtin_amdgcn_readfirstlane(node);   // provably wave-uniform -> scalar loads
    int lane = threadIdx.x & 63;
    int c = lane * 2;

    float di = dinv[node];
    uint sv = *(const uint*)&zh[(size_t)node * HID + c];
    float s0 = bf_lo(sv), s1 = bf_hi(sv);

    int cnt = counts[node];
    const int* ep = srcs + offsets[node];
    int i = 0;
    for (; i + 8 <= cnt; i += 8) {
        uint u0 = *(const uint*)&zh[(size_t)ep[i + 0] * HID + c];
        uint u1 = *(const uint*)&zh[(size_t)ep[i + 1] * HID + c];
        uint u2 = *(const uint*)&zh[(size_t)ep[i + 2] * HID + c];
        uint u3 = *(const uint*)&zh[(size_t)ep[i + 3] * HID + c];
        uint u4 = *(const uint*)&zh[(size_t)ep[i + 4] * HID + c];
        uint u5 = *(const uint*)&zh[(size_t)ep[i + 5] * HID + c];
        uint u6 = *(const uint*)&zh[(size_t)ep[i + 6] * HID + c];
        uint u7 = *(const uint*)&zh[(size_t)ep[i + 7] * HID + c];
        s0 += bf_lo(u0) + bf_lo(u1) + bf_lo(u2) + bf_lo(u3)
            + bf_lo(u4) + bf_lo(u5) + bf_lo(u6) + bf_lo(u7);
        s1 += bf_hi(u0) + bf_hi(u1) + bf_hi(u2) + bf_hi(u3)
            + bf_hi(u4) + bf_hi(u5) + bf_hi(u6) + bf_hi(u7);
    }
    for (; i < cnt; ++i) {
        uint u0 = *(const uint*)&zh[(size_t)ep[i] * HID + c];
        s0 += bf_lo(u0);
        s1 += bf_hi(u0);
    }

    float2 bv = *(const float2*)&bias[c];
    float r0 = fmaxf(fmaf(di, s0, bv.x), 0.0f);
    float r1 = fmaxf(fmaf(di, s1, bv.y), 0.0f);
    uint pk = (uint)f2bf(r0) | ((uint)f2bf(r1) << 16);
    *(uint*)&out[(size_t)node * HID + c] = pk;
}

__global__ void copy_k(const float* __restrict__ in, float* __restrict__ out, int n4) {
    int i = blockIdx.x * blockDim.x + threadIdx.x;
    if (i < n4) ((float4*)out)[i] = ((const float4*)in)[i];
}

// ---------------------------------------------------------------------------
// MFMA GEMM: C_bf16[n][128] = op( A[n][K] @ B_f32[K][128] )
//   AF32:  A is f32 (converted in-kernel), else bf16
//   BIAS:  add bias[col]
//   SCALE: multiply row by dinv[row] (pre-scaled Z-hat for GCN)
// block: 256 threads = 4 waves; tile 64 rows x 128 cols
// ---------------------------------------------------------------------------
template <int K, bool AF32, bool BIAS, bool SCALE>
__global__ __launch_bounds__(256) void mfma_gemm_k(
    const void* __restrict__ Araw, const float* __restrict__ B,
    const float* __restrict__ bias, const float* __restrict__ dinv,
    ushort* __restrict__ C, int n)
{
    constexpr int KSTEPS = K / 32;
    __shared__ ushort Bt[128][136];

    const int tid = threadIdx.x;
    const int wid = tid >> 6;
    const int lane = tid & 63;
    const int brow = blockIdx.x * 64;

    // stage B transposed (f32 -> bf16): Bt[col][k] = B[k][col]
    for (int i = tid; i < K * 64; i += 256) {
        float2 v = ((const float2*)B)[i];
        int idx = 2 * i;
        int k = idx >> 7;
        int cc = idx & 127;
        Bt[cc][k] = f2bf(v.x);
        Bt[cc + 1][k] = f2bf(v.y);
    }
    __syncthreads();

    // A fragment: row = l&15 (+wave offset), k-chunk = (l>>4)*8
    const int arow = brow + wid * 16 + (lane & 15);
    const int rowc = (arow < n) ? arow : (n - 1);

    f32x4 acc[8];
    #pragma unroll
    for (int j = 0; j < 8; ++j) acc[j] = (f32x4){0.f, 0.f, 0.f, 0.f};

    #pragma unroll
    for (int kt = 0; kt < KSTEPS; ++kt) {
        short8v a;
        if (AF32) {
            const float* ap = (const float*)Araw + (size_t)rowc * K + (lane >> 4) * 8 + kt * 32;
            float4 f0 = *(const float4*)ap;
            float4 f1 = *(const float4*)(ap + 4);
            a[0] = (short)f2bf(f0.x); a[1] = (short)f2bf(f0.y);
            a[2] = (short)f2bf(f0.z); a[3] = (short)f2bf(f0.w);
            a[4] = (short)f2bf(f1.x); a[5] = (short)f2bf(f1.y);
            a[6] = (short)f2bf(f1.z); a[7] = (short)f2bf(f1.w);
        } else {
            const ushort* ap = (const ushort*)Araw + (size_t)rowc * K + (lane >> 4) * 8 + kt * 32;
            a = *(const short8v*)ap;
        }
        #pragma unroll
        for (int j = 0; j < 8; ++j) {
            short8v b = *(const short8v*)&Bt[j * 16 + (lane & 15)][kt * 32 + (lane >> 4) * 8];
            acc[j] = __builtin_amdgcn_mfma_f32_16x16x32_bf16(a, b, acc[j], 0, 0, 0);
        }
    }

    // epilogue: C/D layout col = lane&15, row = (lane>>4)*4 + reg
    const int r0 = brow + wid * 16 + (lane >> 4) * 4;
    const int cl = lane & 15;
    float dsc[4];
    if (SCALE) {
        #pragma unroll
        for (int r = 0; r < 4; ++r) dsc[r] = (r0 + r < n) ? dinv[r0 + r] : 0.0f;
    }
    #pragma unroll
    for (int j = 0; j < 8; ++j) {
        int col = j * 16 + cl;
        float bv = BIAS ? bias[col] : 0.0f;
        #pragma unroll
        for (int r = 0; r < 4; ++r) {
            int row = r0 + r;
            if (row < n) {
                float v = acc[j][r];
                if (SCALE) v *= dsc[r];
                if (BIAS) v += bv;
                C[(size_t)row * HID + col] = f2bf(v);
            }
        }
    }
}

// ---------------------------------------------------------------------------
// output GEMM: C_f32[n][24] = A_bf16[n][128] @ W_f32[128][24] + b
// ---------------------------------------------------------------------------
__global__ __launch_bounds__(256) void gemm_out_k(
    const ushort* __restrict__ A, const float* __restrict__ W,
    const float* __restrict__ bias, float* __restrict__ C, int n)
{
    __shared__ float Wls[HID][HORIZON];
    __shared__ float As[32][132];

    const int tid = threadIdx.x;
    const int brow = blockIdx.x * 32;

    for (int i = tid; i < HID * HORIZON; i += 256)
        Wls[i / HORIZON][i % HORIZON] = W[i];

    for (int i = tid; i < 32 * 64; i += 256) {     // uints: 32 rows * 128 cols / 2
        int idx = 2 * i;
        int r = idx >> 7;
        int cc = idx & 127;
        int row = brow + r;
        uint v = 0;
        if (row < n) v = *(const uint*)&A[(size_t)row * HID + cc];
        As[r][cc] = bf_lo(v);
        As[r][cc + 1] = bf_hi(v);
    }
    __syncthreads();

    const int rowi = tid >> 3;
    const int cg = tid & 7;
    const int c0 = cg * 3;
    float a0 = bias[c0 + 0], a1 = bias[c0 + 1], a2 = bias[c0 + 2];
    #pragma unroll 8
    for (int k = 0; k < HID; ++k) {
        float a = As[rowi][k];
        a0 = fmaf(a, Wls[k][c0 + 0], a0);
        a1 = fmaf(a, Wls[k][c0 + 1], a1);
        a2 = fmaf(a, Wls[k][c0 + 2], a2);
    }
    int row = brow + rowi;
    if (row < n) {
        C[(size_t)row * HORIZON + c0 + 0] = a0;
        C[(size_t)row * HORIZON + c0 + 1] = a1;
        C[(size_t)row * HORIZON + c0 + 2] = a2;
    }
}

// ---------------------------------------------------------------------------
extern "C" void kernel_launch(void* const* d_in, const int* in_sizes, int n_in,
                              void* d_out, int out_size, void* d_ws, size_t ws_size,
                              hipStream_t stream) {
    const float* x     = (const float*)d_in[0];
    const float* y     = (const float*)d_in[1];
    const int*   ei    = (const int*)d_in[2];     // int64 in ref -> int32 on device
    const float* W_in  = (const float*)d_in[3];
    const float* b_in  = (const float*)d_in[4];
    const float* Ws    = (const float*)d_in[5];
    const float* bs    = (const float*)d_in[6];
    const float* W_out = (const float*)d_in[7];
    const float* b_out = (const float*)d_in[8];
    float* out = (float*)d_out;

    const int n = in_sizes[0] / LOOKBACK;
    const int E = in_sizes[2] / 2;
    const int* src = ei;
    const int* dst = ei + E;
    const int nb = (n + 1023) / 1024;

    // workspace layout
    char* p = (char*)d_ws;
    float*  dinv    = (float*)p;   p += (size_t)n * 4;
    int*    counts  = (int*)p;     p += (size_t)n * 4;
    int*    offsets = (int*)p;     p += (size_t)n * 4;
    int*    cursor  = (int*)p;     p += (size_t)n * 4;
    int*    bsum    = (int*)p;     p += (size_t)1024 * 4;
    int*    srcs    = (int*)p;     p += (size_t)E * 4;
    ushort* bufA    = (ushort*)p;  p += (size_t)n * HID * 2;
    ushort* bufB    = (ushort*)p;

    const int B = 256;
    // ---- CSR build ----
    zero_counts_k<<<(n + B - 1) / B, B, 0, stream>>>(counts, n);
    hist_k<<<(E + B - 1) / B, B, 0, stream>>>(dst, counts, E);
    dinv_k<<<(n + B - 1) / B, B, 0, stream>>>(counts, dinv, n);
    bsum_k<<<nb, 1024, 0, stream>>>(counts, bsum, n);
    scan_bsum_k<<<1, 1024, 0, stream>>>(bsum, nb);
    scan_local_k<<<nb, 1024, 0, stream>>>(counts, bsum, offsets, cursor, n);
    scatter_k<<<(E + B - 1) / B, B, 0, stream>>>(src, dst, cursor, srcs, E);

    // ---- network ----
    const int gemm_grid = (n + 63) / 64;
    // input projection: h = x @ W_in + b_in  (f32 A, bias, no scale)
    mfma_gemm_k<LOOKBACK, true, true, false><<<gemm_grid, 256, 0, stream>>>(
        x, W_in, b_in, nullptr, bufA, n);

    const int agg_grid = (n * 64 + 255) / 256;
    for (int l = 0; l < NLAYERS; ++l) {
        // z-hat = dinv .* (h @ W_l)  (bf16 A, no bias, scale)
        mfma_gemm_k<HID, false, false, true><<<gemm_grid, 256, 0, stream>>>(
            bufA, Ws + (size_t)l * HID * HID, nullptr, dinv, bufB, n);
        agg_k<<<agg_grid, 256, 0, stream>>>(bufB, bufA, dinv, offsets, counts,
                                            srcs, bs + (size_t)l * HID, n);
    }

    gemm_out_k<<<(n + 31) / 32, 256, 0, stream>>>(bufA, W_out, b_out, out, n);

    const int y4 = n * HORIZON / 4;
    copy_k<<<(y4 + B - 1) / B, B, 0, stream>>>(y, out + (size_t)n * HORIZON, y4);
}